// Round 2
// baseline (664.577 us; speedup 1.0000x reference)
//
#include <hip/hip_runtime.h>

#define IN   784
#define HID  128
#define OUT  10
#define THR  0.5f

#define TPB   256
#define RPB   64            // rows per block: 4 threads cooperate on one row
#define NPASS (IN / 16)     // 49 passes; each pass = 16 cols/row, 4 cols/thread

// ---------------- kernel 1: fold the network into M[10][784], c[10] ---------
// y[b,o] = c[o] - (1/784) * sum_i x[b,i] * M[o,i]
// M[o,i] = sum_h W2[o,h] * ternarize(W1[h,i]);  c[o] = b2[o] + sum_h W2[o,h]
__global__ void build_M(const float* __restrict__ W1, const float* __restrict__ W2,
                        const float* __restrict__ b2, float* __restrict__ M,
                        float* __restrict__ c) {
    const int i = blockIdx.x * 64 + threadIdx.x;
    if (blockIdx.x == 0 && threadIdx.x < OUT) {
        float s = b2[threadIdx.x];
        for (int h = 0; h < HID; ++h) s += W2[threadIdx.x * HID + h];
        c[threadIdx.x] = s;
    }
    if (i < IN) {
        float acc[OUT];
#pragma unroll
        for (int o = 0; o < OUT; ++o) acc[o] = 0.f;
#pragma unroll 8
        for (int h = 0; h < HID; ++h) {
            const float w = W1[h * IN + i];                 // coalesced across i
            const float t = (w > THR) ? 1.f : ((w < -THR) ? -1.f : 0.f);
#pragma unroll
            for (int o = 0; o < OUT; ++o)
                acc[o] = fmaf(W2[o * HID + h], t, acc[o]);  // W2 uniform -> s_load
        }
#pragma unroll
        for (int o = 0; o < OUT; ++o) M[o * IN + i] = acc[o];
    }
}

// ---------------- kernel 2: streaming y = c - (x @ M^T)/784 -----------------
// No LDS, no barriers. Thread t: row r = blk*64 + t/4, column subset
// {16p + 4u + j : p in [0,49), j in [0,4)} with u = t&3.
// x loads: 4 consecutive lanes read contiguous 64 B -> coalesced.
// M loads: one 64 B line per wave-instr, L1/L2-hit (M is 31 KB, hot).
// Final: shfl_xor over the 4-lane group combines partials.
__global__ void __launch_bounds__(TPB, 6)
fused_fwd(const float* __restrict__ x, const float* __restrict__ M,
          const float* __restrict__ c, float* __restrict__ y) {
    const int t = threadIdx.x;
    const int u = t & 3;
    const int r = blockIdx.x * RPB + (t >> 2);
    const float* xp = x + (size_t)r * IN + u * 4;
    const float* mp = M + u * 4;

    float acc[OUT];
#pragma unroll
    for (int o = 0; o < OUT; ++o) acc[o] = 0.f;

    // 2-deep software pipeline on the streaming x loads
    float4 xa = *reinterpret_cast<const float4*>(xp);
    float4 xb = *reinterpret_cast<const float4*>(xp + 16);

#pragma unroll 1
    for (int p = 0; p < NPASS; ++p) {
        const float4 xv = xa;
        xa = xb;
        if (p + 2 < NPASS)
            xb = *reinterpret_cast<const float4*>(xp + (p + 2) * 16);

        const float* m0 = mp + p * 16;
#pragma unroll
        for (int o = 0; o < OUT; ++o) {
            const float4 m = *reinterpret_cast<const float4*>(m0 + o * IN);
            acc[o] = fmaf(xv.x, m.x, acc[o]);
            acc[o] = fmaf(xv.y, m.y, acc[o]);
            acc[o] = fmaf(xv.z, m.z, acc[o]);
            acc[o] = fmaf(xv.w, m.w, acc[o]);
        }
    }

    // combine the 4 per-row partials (lanes 4k..4k+3)
#pragma unroll
    for (int o = 0; o < OUT; ++o) {
        acc[o] += __shfl_xor(acc[o], 1);
        acc[o] += __shfl_xor(acc[o], 2);
    }

    if (u == 0) {
        const float inv = 1.0f / (float)IN;
#pragma unroll
        for (int o = 0; o < OUT; ++o)
            y[(size_t)r * OUT + o] = c[o] - acc[o] * inv;
    }
}

extern "C" void kernel_launch(void* const* d_in, const int* in_sizes, int n_in,
                              void* d_out, int out_size, void* d_ws, size_t ws_size,
                              hipStream_t stream) {
    const float* x  = (const float*)d_in[0];
    const float* W1 = (const float*)d_in[1];
    const float* W2 = (const float*)d_in[2];
    const float* b2 = (const float*)d_in[3];
    float* y = (float*)d_out;

    float* M = (float*)d_ws;        // OUT*IN floats = 31.4 KB scratch
    float* c = M + OUT * IN;        // OUT floats

    const int B = in_sizes[0] / IN; // 131072

    build_M<<<(IN + 63) / 64, 64, 0, stream>>>(W1, W2, b2, M, c);
    fused_fwd<<<B / RPB, TPB, 0, stream>>>(x, M, c, y);
}

// Round 3
// 570.276 us; speedup vs baseline: 1.1654x; 1.1654x over previous
//
#include <hip/hip_runtime.h>

#define IN   784
#define HID  128
#define OUT  10
#define THR  0.5f

#define TPB  256
#define RPB  64     // rows per block; one row per lane, 4 waves split K

typedef const float __attribute__((address_space(1)))* gas1_t;
typedef float       __attribute__((address_space(3)))* las3_t;

// ---------------- kernel 1: fold the network into M[10][784], c[10] ---------
// y[b,o] = c[o] - (1/784) * sum_i x[b,i] * M[o,i]
__global__ void build_M(const float* __restrict__ W1, const float* __restrict__ W2,
                        const float* __restrict__ b2, float* __restrict__ M,
                        float* __restrict__ c) {
    const int i = blockIdx.x * 64 + threadIdx.x;
    if (blockIdx.x == 0 && threadIdx.x < OUT) {
        float s = b2[threadIdx.x];
        for (int h = 0; h < HID; ++h) s += W2[threadIdx.x * HID + h];
        c[threadIdx.x] = s;
    }
    if (i < IN) {
        float acc[OUT];
#pragma unroll
        for (int o = 0; o < OUT; ++o) acc[o] = 0.f;
#pragma unroll 8
        for (int h = 0; h < HID; ++h) {
            const float w = W1[h * IN + i];
            const float t = (w > THR) ? 1.f : ((w < -THR) ? -1.f : 0.f);
#pragma unroll
            for (int o = 0; o < OUT; ++o)
                acc[o] = fmaf(W2[o * HID + h], t, acc[o]);
        }
#pragma unroll
        for (int o = 0; o < OUT; ++o) M[o * IN + i] = acc[o];
    }
}

// ---------------- kernel 2: y = c - (x @ M^T)/784 ---------------------------
// Wave-independent K-split: wave w of a block owns cols [colbase, colbase+ncols)
// of the block's 64 rows (w0: 208 cols = 13 chunks of 16; w1-3: 192 = 12).
// Per chunk (64 rows x 16 cols = 4 KB): 4x global_load_lds_dwordx4 (1 KB each,
// coalesced 64B row segments), double-buffered with s_waitcnt vmcnt(4).
// LDS slot-swizzle (global side): slot s of row r stores col-group
// (s - (r>>1)) & 3, so reading col-group g hits all 8 LDS 4-bank sets (b128
// optimum). M reads are wave-uniform -> s_load (scalar pipe, zero VMEM).
__global__ void __launch_bounds__(TPB, 5)
fused_fwd(const float* __restrict__ x, const float* __restrict__ M,
          const float* __restrict__ c, float* __restrict__ y) {
    __shared__ float sm[4 * 2048];                 // 32 KB: 2 KB-float region/wave

    const int tid  = threadIdx.x;
    const int lane = tid & 63;
    const int w    = __builtin_amdgcn_readfirstlane(tid >> 6);
    const int row0 = blockIdx.x * RPB;

    const int nch     = (w == 0) ? 13 : 12;        // chunks of 16 cols
    const int colbase = w * 192 + (w ? 16 : 0);    // 0 / 208 / 400 / 592

    // ---- global-side staging address (write swizzle) ----
    // instr i covers rows 16i..16i+15; lane: row16 = lane>>2, slot = lane&3
    // stored col-group cw = (slot - ((lane>>3)&3)) & 3   [(row>>1)&3 == (lane>>3)&3]
    const int cw = ((lane & 3) - ((lane >> 3) & 3)) & 3;
    const float* gl = x + (size_t)(row0 + (lane >> 2)) * IN + colbase + 4 * cw;

    float* lbase = &sm[w * 2048];                  // this wave's private region

    // ---- LDS read offsets (float index in wave region): row=lane, group g ----
    const int rsw = (lane >> 1) & 3;
    int roff[4];
#pragma unroll
    for (int g = 0; g < 4; ++g) roff[g] = 16 * lane + 4 * ((g + rsw) & 3);

    float acc[OUT];
#pragma unroll
    for (int o = 0; o < OUT; ++o) acc[o] = 0.f;

#define ISSUE(j, buf)                                                         \
    {                                                                         \
        float* lp = lbase + (buf) * 1024;                                     \
        const float* gp = gl + (j) * 16;                                      \
        _Pragma("unroll")                                                     \
        for (int i = 0; i < 4; ++i)                                           \
            __builtin_amdgcn_global_load_lds((gas1_t)(gp + i * 16 * IN),      \
                                             (las3_t)(lp + i * 256), 16, 0, 0); \
    }

    ISSUE(0, 0)
    ISSUE(1, 1)

#pragma unroll 1
    for (int j = 0; j < nch; ++j) {
        if (j + 1 < nch) __builtin_amdgcn_s_waitcnt(0x0F74);  // vmcnt(4): chunk j done
        else             __builtin_amdgcn_s_waitcnt(0x0F70);  // vmcnt(0): last chunk
        __builtin_amdgcn_sched_barrier(0);

        const int buf = (j & 1) * 1024;
        float4 xv[4];
#pragma unroll
        for (int g = 0; g < 4; ++g)
            xv[g] = *reinterpret_cast<const float4*>(lbase + buf + roff[g]);

        const float* mp = M + colbase + j * 16;    // wave-uniform -> s_load
#pragma unroll
        for (int g = 0; g < 4; ++g) {
#pragma unroll
            for (int o = 0; o < OUT; ++o) {
                const float4 m = *reinterpret_cast<const float4*>(mp + o * IN + 4 * g);
                acc[o] = fmaf(xv[g].x, m.x, acc[o]);
                acc[o] = fmaf(xv[g].y, m.y, acc[o]);
                acc[o] = fmaf(xv[g].z, m.z, acc[o]);
                acc[o] = fmaf(xv[g].w, m.w, acc[o]);
            }
        }
        __builtin_amdgcn_sched_barrier(0);         // keep issue below the consumes (WAR)
        if (j + 2 < nch) ISSUE(j + 2, j & 1)
    }

    // ---- combine the 4 K-partials (one barrier per block) ----
#pragma unroll
    for (int o = 0; o < OUT; ++o) lbase[lane * 10 + o] = acc[o];
    __syncthreads();

    const float inv = 1.0f / (float)IN;
#pragma unroll 1
    for (int idx = tid; idx < RPB * OUT; idx += TPB) {   // idx == row*10 + o
        const float s = sm[idx] + sm[2048 + idx] + sm[4096 + idx] + sm[6144 + idx];
        y[(size_t)row0 * OUT + idx] = c[idx % 10] - s * inv;
    }
#undef ISSUE
}

extern "C" void kernel_launch(void* const* d_in, const int* in_sizes, int n_in,
                              void* d_out, int out_size, void* d_ws, size_t ws_size,
                              hipStream_t stream) {
    const float* x  = (const float*)d_in[0];
    const float* W1 = (const float*)d_in[1];
    const float* W2 = (const float*)d_in[2];
    const float* b2 = (const float*)d_in[3];
    float* y = (float*)d_out;

    float* M = (float*)d_ws;        // OUT*IN floats
    float* c = M + OUT * IN;        // OUT floats

    const int B = in_sizes[0] / IN; // 131072

    build_M<<<(IN + 63) / 64, 64, 0, stream>>>(W1, W2, b2, M, c);
    fused_fwd<<<B / RPB, TPB, 0, stream>>>(x, M, c, y);
}